// Round 3
// baseline (602.322 us; speedup 1.0000x reference)
//
#include <hip/hip_runtime.h>

#define NN 50000
#define NE 800000
#define NG 128
#define IND 5
#define HID 64
#define EPSV 1e-5f
#define SCAN_T 1024

// ---- fused degree accumulate + dst histogram ----
__global__ void k_deg_hist(const int* __restrict__ dst, const float* __restrict__ w,
                           float* deg, int* hist /* row_ptr, counts at d+1 */) {
    int e = blockIdx.x * blockDim.x + threadIdx.x;
    if (e < NE) {
        int d = dst[e];
        atomicAdd(&deg[d], w[e]);
        atomicAdd(&hist[d + 1], 1);
    }
}

// deg was zero-init; self-loop adds 1 -> dinv = rsqrt(deg+1)
__global__ void k_dinv(float* deg) {
    int i = blockIdx.x * blockDim.x + threadIdx.x;
    if (i < NN) deg[i] = rsqrtf(deg[i] + 1.0f);
}

// ---- single-block inclusive scan of row_ptr[0..NN] (row_ptr[0]=0 pre-zeroed) ----
__global__ void k_scan(int* __restrict__ row_ptr) {
    __shared__ int tot[SCAN_T];
    int t = threadIdx.x;
    const int CH = (NN + 1 + SCAN_T - 1) / SCAN_T;
    int beg = t * CH;
    int end = beg + CH; if (end > NN + 1) end = NN + 1;
    int s = 0;
    for (int i = beg; i < end; i++) s += row_ptr[i];
    tot[t] = s;
    __syncthreads();
    for (int off = 1; off < SCAN_T; off <<= 1) {
        int v = (t >= off) ? tot[t - off] : 0;
        __syncthreads();
        tot[t] += v;
        __syncthreads();
    }
    int run = (t > 0) ? tot[t - 1] : 0;
    for (int i = beg; i < end; i++) { run += row_ptr[i]; row_ptr[i] = run; }
}

// ---- bin edges into CSR (src + fused norm), keyed by dst ----
__global__ void k_fill(const int* __restrict__ src, const int* __restrict__ dst,
                       const float* __restrict__ ew, const float* __restrict__ dinv,
                       const int* __restrict__ row_ptr, int* cursor, int2* __restrict__ csr) {
    int e = blockIdx.x * blockDim.x + threadIdx.x;
    if (e >= NE) return;
    int s = src[e], d = dst[e];
    int pos = row_ptr[d] + atomicAdd(&cursor[d], 1);
    float norm = dinv[s] * ew[e] * dinv[d];
    csr[pos] = make_int2(s, __float_as_int(norm));
}

// ---------------- x @ W1  (N x 5 @ 5 x 64) ----------------
__global__ void k_gemm1(const float* __restrict__ x, const float* __restrict__ W1,
                        float* __restrict__ h) {
    __shared__ float Ws[IND * HID];
    for (int j = threadIdx.x; j < IND * HID; j += blockDim.x) Ws[j] = W1[j];
    __syncthreads();
    int gid = blockIdx.x * blockDim.x + threadIdx.x;
    if (gid >= NN * HID) return;
    int n = gid >> 6, hc = gid & 63;
    const float* xr = &x[n * IND];
    float acc = 0.f;
#pragma unroll
    for (int k = 0; k < IND; k++) acc += xr[k] * Ws[k * HID + hc];
    h[gid] = acc;
}

// ---------------- a @ W2  (N x 64 @ 64 x 64) ----------------
__global__ void k_gemm2(const float* __restrict__ a, const float* __restrict__ W,
                        float* __restrict__ out) {
    __shared__ float Ws[HID * HID];
    for (int j = threadIdx.x; j < HID * HID; j += blockDim.x) Ws[j] = W[j];
    __syncthreads();
    int gid = blockIdx.x * blockDim.x + threadIdx.x;
    if (gid >= NN * HID) return;
    int n = gid >> 6, hc = gid & 63;
    const float* ar = &a[n * HID];
    float acc = 0.f;
#pragma unroll 8
    for (int k = 0; k < HID; k++) acc += ar[k] * Ws[k * HID + hc];
    out[gid] = acc;
}

// ---- gather aggregation + fused epilogue.  LAYER=1: bn1+relu -> outv.
//      LAYER=2: bn2+relu -> pool atomics.
//  Edge loop is unrolled 8x with batched loads: 8 csr entries issued together,
//  then 8 dependent feature gathers issued together -> ~8x memory-level
//  parallelism vs the serial loop (which was latency-bound at VALUBusy 2%). ----
template <int LAYER>
__global__ void k_gather(const float* __restrict__ h, const float* __restrict__ dinv,
                         const int* __restrict__ row_ptr, const int2* __restrict__ csr,
                         const float* __restrict__ bias,
                         const float* __restrict__ gamma, const float* __restrict__ beta,
                         const float* __restrict__ mean, const float* __restrict__ var,
                         const int* __restrict__ batch,
                         float* __restrict__ outv, float* pool, float* cnt) {
    int gid = blockIdx.x * blockDim.x + threadIdx.x;  // 16 lanes per node
    if (gid >= NN * 16) return;
    int n = gid >> 4, c4 = gid & 15;
    const float4* h4 = (const float4*)h;
    int beg = row_ptr[n], end = row_ptr[n + 1];

    // hoisted self-loop term (issues early, overlaps with loop)
    float di = dinv[n];
    float coef = di * di;
    float4 sv = h4[n * 16 + c4];
    float4 bv = ((const float4*)bias)[c4];
    float4 acc;
    acc.x = bv.x + coef * sv.x;
    acc.y = bv.y + coef * sv.y;
    acc.z = bv.z + coef * sv.z;
    acc.w = bv.w + coef * sv.w;

    int i = beg;
    for (; i + 8 <= end; i += 8) {
        int2 ee[8];
#pragma unroll
        for (int j = 0; j < 8; j++) ee[j] = csr[i + j];
        float4 vv[8];
#pragma unroll
        for (int j = 0; j < 8; j++) vv[j] = h4[ee[j].x * 16 + c4];
#pragma unroll
        for (int j = 0; j < 8; j++) {
            float w = __int_as_float(ee[j].y);
            acc.x += w * vv[j].x; acc.y += w * vv[j].y;
            acc.z += w * vv[j].z; acc.w += w * vv[j].w;
        }
    }
    if (i + 4 <= end) {
        int2 ee[4];
#pragma unroll
        for (int j = 0; j < 4; j++) ee[j] = csr[i + j];
        float4 vv[4];
#pragma unroll
        for (int j = 0; j < 4; j++) vv[j] = h4[ee[j].x * 16 + c4];
#pragma unroll
        for (int j = 0; j < 4; j++) {
            float w = __int_as_float(ee[j].y);
            acc.x += w * vv[j].x; acc.y += w * vv[j].y;
            acc.z += w * vv[j].z; acc.w += w * vv[j].w;
        }
        i += 4;
    }
    for (; i < end; i++) {
        int2 ef = csr[i];
        float w = __int_as_float(ef.y);
        float4 hv = h4[ef.x * 16 + c4];
        acc.x += w * hv.x; acc.y += w * hv.y;
        acc.z += w * hv.z; acc.w += w * hv.w;
    }

    int c0 = c4 * 4;
    float r0 = fmaxf((acc.x - mean[c0 + 0]) * rsqrtf(var[c0 + 0] + EPSV) * gamma[c0 + 0] + beta[c0 + 0], 0.f);
    float r1 = fmaxf((acc.y - mean[c0 + 1]) * rsqrtf(var[c0 + 1] + EPSV) * gamma[c0 + 1] + beta[c0 + 1], 0.f);
    float r2 = fmaxf((acc.z - mean[c0 + 2]) * rsqrtf(var[c0 + 2] + EPSV) * gamma[c0 + 2] + beta[c0 + 2], 0.f);
    float r3 = fmaxf((acc.w - mean[c0 + 3]) * rsqrtf(var[c0 + 3] + EPSV) * gamma[c0 + 3] + beta[c0 + 3], 0.f);
    if (LAYER == 1) {
        ((float4*)outv)[gid] = make_float4(r0, r1, r2, r3);
    } else {
        int g = batch[n];
        float* pp = &pool[g * HID + c0];
        atomicAdd(pp + 0, r0);
        atomicAdd(pp + 1, r1);
        atomicAdd(pp + 2, r2);
        atomicAdd(pp + 3, r3);
        if (c4 == 0) atomicAdd(&cnt[g], 1.0f);
    }
}

// ---------------- final MLP ----------------
__global__ void k_mlp(const float* __restrict__ pool_sums, const float* __restrict__ cnt,
                      const float* __restrict__ l1W, const float* __restrict__ l1b,
                      const float* __restrict__ l2W, const float* __restrict__ l2b,
                      float* __restrict__ outp) {
    int g = blockIdx.x * blockDim.x + threadIdx.x;
    if (g >= NG) return;
    float c = fmaxf(cnt[g], 1.0f);
    float inv = 1.0f / c;
    float p[HID];
#pragma unroll
    for (int k = 0; k < HID; k++) p[k] = pool_sums[g * HID + k] * inv;
    float acc = 0.f;
    for (int j = 0; j < HID / 2; j++) {
        float z = l1b[j];
#pragma unroll 8
        for (int k = 0; k < HID; k++) z += p[k] * l1W[k * (HID / 2) + j];
        acc += fmaxf(z, 0.f) * l2W[j];
    }
    outp[g] = acc + l2b[0];
}

extern "C" void kernel_launch(void* const* d_in, const int* in_sizes, int n_in,
                              void* d_out, int out_size, void* d_ws, size_t ws_size,
                              hipStream_t stream) {
    const float* x   = (const float*)d_in[0];
    const int*   ei  = (const int*)d_in[1];
    const float* ew  = (const float*)d_in[2];
    const int*   bat = (const int*)d_in[3];
    const float* W1  = (const float*)d_in[4];
    const float* b1  = (const float*)d_in[5];
    const float* W2  = (const float*)d_in[6];
    const float* b2  = (const float*)d_in[7];
    const float* g1  = (const float*)d_in[8];
    const float* be1 = (const float*)d_in[9];
    const float* m1  = (const float*)d_in[10];
    const float* v1  = (const float*)d_in[11];
    const float* g2  = (const float*)d_in[12];
    const float* be2 = (const float*)d_in[13];
    const float* m2  = (const float*)d_in[14];
    const float* v2  = (const float*)d_in[15];
    const float* l1W = (const float*)d_in[16];
    const float* l1b = (const float*)d_in[17];
    const float* l2W = (const float*)d_in[18];
    const float* l2b = (const float*)d_in[19];
    float* out = (float*)d_out;

    const int* src = ei;
    const int* dst = ei + NE;

    // ---- workspace layout (4-byte units) ----
    float* f = (float*)d_ws;
    float* dinv    = f + 0;               // 50000  (zeroed; becomes rsqrt(deg+1))
    float* pool    = f + 50000;           // 8192
    float* cnt     = f + 58192;           // 128
    int*   row_ptr = (int*)(f + 58320);   // 50001
    int*   cursor  = (int*)(f + 108321);  // 50000
    // zero region = [0, 158321) floats
    int2*  csr     = (int2*)(f + 158336); // 800000 int2 (8B aligned)
    float* bufA    = f + 1758336;         // NN*HID (projected h)
    float* bufC    = f + 4958336;         // NN*HID (layer-1 activated)
    // total = 8158336 floats = 32.6 MB

    const int BLK = 256;
    const int gN   = (NN + BLK - 1) / BLK;
    const int gE   = (NE + BLK - 1) / BLK;
    const int gNH  = (NN * HID + BLK - 1) / BLK;
    const int gN16 = (NN * 16 + BLK - 1) / BLK;

    hipMemsetAsync(d_ws, 0, 158321 * sizeof(float), stream);

    // normalization + CSR build (shared across both conv layers)
    k_deg_hist<<<gE, BLK, 0, stream>>>(dst, ew, dinv, row_ptr);
    k_dinv<<<gN, BLK, 0, stream>>>(dinv);
    k_scan<<<1, SCAN_T, 0, stream>>>(row_ptr);
    k_fill<<<gE, BLK, 0, stream>>>(src, dst, ew, dinv, row_ptr, cursor, csr);

    // layer 1: project, gather(+bn1+relu fused)
    k_gemm1<<<gNH, BLK, 0, stream>>>(x, W1, bufA);
    k_gather<1><<<gN16, BLK, 0, stream>>>(bufA, dinv, row_ptr, csr, b1,
                                          g1, be1, m1, v1, bat, bufC, pool, cnt);

    // layer 2: project, gather(+bn2+relu+pool fused)
    k_gemm2<<<gNH, BLK, 0, stream>>>(bufC, W2, bufA);
    k_gather<2><<<gN16, BLK, 0, stream>>>(bufA, dinv, row_ptr, csr, b2,
                                          g2, be2, m2, v2, bat, nullptr, pool, cnt);

    // MLP head
    k_mlp<<<1, 128, 0, stream>>>(pool, cnt, l1W, l1b, l2W, l2b, out);
}

// Round 4
// 588.270 us; speedup vs baseline: 1.0239x; 1.0239x over previous
//
#include <hip/hip_runtime.h>

#define NN 50000
#define NE 800000
#define NG 128
#define IND 5
#define HID 64
#define EPSV 1e-5f
#define SCAN_T 1024

// ---- fused degree accumulate + dst histogram ----
__global__ void k_deg_hist(const int* __restrict__ dst, const float* __restrict__ w,
                           float* deg, int* hist) {
    int e = blockIdx.x * blockDim.x + threadIdx.x;
    if (e < NE) {
        int d = dst[e];
        atomicAdd(&deg[d], w[e]);
        atomicAdd(&hist[d + 1], 1);
    }
}

// deg was zero-init; self-loop adds 1 -> dinv = rsqrt(deg+1)
__global__ void k_dinv(float* deg) {
    int i = blockIdx.x * blockDim.x + threadIdx.x;
    if (i < NN) deg[i] = rsqrtf(deg[i] + 1.0f);
}

// ---- single-block inclusive scan of row_ptr[0..NN] ----
__global__ void k_scan(int* __restrict__ row_ptr) {
    __shared__ int tot[SCAN_T];
    int t = threadIdx.x;
    const int CH = (NN + 1 + SCAN_T - 1) / SCAN_T;
    int beg = t * CH;
    int end = beg + CH; if (end > NN + 1) end = NN + 1;
    int s = 0;
    for (int i = beg; i < end; i++) s += row_ptr[i];
    tot[t] = s;
    __syncthreads();
    for (int off = 1; off < SCAN_T; off <<= 1) {
        int v = (t >= off) ? tot[t - off] : 0;
        __syncthreads();
        tot[t] += v;
        __syncthreads();
    }
    int run = (t > 0) ? tot[t - 1] : 0;
    for (int i = beg; i < end; i++) { run += row_ptr[i]; row_ptr[i] = run; }
}

// ---- bin edges into CSR (src + fused norm), keyed by dst ----
__global__ void k_fill(const int* __restrict__ src, const int* __restrict__ dst,
                       const float* __restrict__ ew, const float* __restrict__ dinv,
                       const int* __restrict__ row_ptr, int* cursor, int2* __restrict__ csr) {
    int e = blockIdx.x * blockDim.x + threadIdx.x;
    if (e >= NE) return;
    int s = src[e], d = dst[e];
    int pos = row_ptr[d] + atomicAdd(&cursor[d], 1);
    float norm = dinv[s] * ew[e] * dinv[d];
    csr[pos] = make_int2(s, __float_as_int(norm));
}

// ---- pad x (N x 5) into px (N x 8, zero-padded) for aligned float4 gathers ----
__global__ void k_pad_x(const float* __restrict__ x, float* __restrict__ px) {
    int n = blockIdx.x * blockDim.x + threadIdx.x;
    if (n >= NN) return;
    float4 a, b;
    a.x = x[n * IND + 0]; a.y = x[n * IND + 1]; a.z = x[n * IND + 2]; a.w = x[n * IND + 3];
    b.x = x[n * IND + 4]; b.y = 0.f; b.z = 0.f; b.w = 0.f;
    ((float4*)px)[n * 2 + 0] = a;
    ((float4*)px)[n * 2 + 1] = b;
}

// ---- layer-1 aggregation on RAW x (aggregate-then-project):
//      xa[n] = coef*px[n] + sum_e norm_e * px[src_e].  16 lanes/node, one EDGE
//      per lane (stride 16) -> 16 edges in flight, csr reads coalesced. ----
__global__ void k_gather_x(const float* __restrict__ px, const float* __restrict__ dinv,
                           const int* __restrict__ row_ptr, const int2* __restrict__ csr,
                           float* __restrict__ xa) {
    int gid = blockIdx.x * blockDim.x + threadIdx.x;  // NN*16 threads
    if (gid >= NN * 16) return;
    int n = gid >> 4, lane16 = gid & 15;
    const float4* p4 = (const float4*)px;
    int beg = row_ptr[n], end = row_ptr[n + 1];
    float4 a0 = make_float4(0.f, 0.f, 0.f, 0.f);
    float4 a1 = make_float4(0.f, 0.f, 0.f, 0.f);
    for (int i = beg + lane16; i < end; i += 16) {
        int2 ef = csr[i];
        float w = __int_as_float(ef.y);
        float4 v0 = p4[ef.x * 2 + 0];
        float4 v1 = p4[ef.x * 2 + 1];
        a0.x += w * v0.x; a0.y += w * v0.y; a0.z += w * v0.z; a0.w += w * v0.w;
        a1.x += w * v1.x;  // only 5 features live; rest are zero pad
    }
    // reduce within the 16-lane group
#pragma unroll
    for (int m = 8; m >= 1; m >>= 1) {
        a0.x += __shfl_xor(a0.x, m); a0.y += __shfl_xor(a0.y, m);
        a0.z += __shfl_xor(a0.z, m); a0.w += __shfl_xor(a0.w, m);
        a1.x += __shfl_xor(a1.x, m);
    }
    if (lane16 == 0) {
        float di = dinv[n];
        float coef = di * di;
        float4 v0 = p4[n * 2 + 0];
        float4 v1 = p4[n * 2 + 1];
        float4 o0, o1;
        o0.x = a0.x + coef * v0.x; o0.y = a0.y + coef * v0.y;
        o0.z = a0.z + coef * v0.z; o0.w = a0.w + coef * v0.w;
        o1.x = a1.x + coef * v1.x; o1.y = 0.f; o1.z = 0.f; o1.w = 0.f;
        ((float4*)xa)[n * 2 + 0] = o0;
        ((float4*)xa)[n * 2 + 1] = o1;
    }
}

// ---- fused projection + bias + bn1 + relu:  out = relu(bn1(xa @ W1 + b1)) ----
__global__ void k_gemm1_fused(const float* __restrict__ xa, const float* __restrict__ W1,
                              const float* __restrict__ b1,
                              const float* __restrict__ gamma, const float* __restrict__ beta,
                              const float* __restrict__ mean, const float* __restrict__ var,
                              float* __restrict__ outv) {
    __shared__ float Ws[IND * HID];
    for (int j = threadIdx.x; j < IND * HID; j += blockDim.x) Ws[j] = W1[j];
    __syncthreads();
    int gid = blockIdx.x * blockDim.x + threadIdx.x;
    if (gid >= NN * HID) return;
    int n = gid >> 6, hc = gid & 63;
    const float* xr = &xa[n * 8];
    float acc = b1[hc];
#pragma unroll
    for (int k = 0; k < IND; k++) acc += xr[k] * Ws[k * HID + hc];
    float r = fmaxf((acc - mean[hc]) * rsqrtf(var[hc] + EPSV) * gamma[hc] + beta[hc], 0.f);
    outv[gid] = r;
}

// ---------------- a @ W2  (N x 64 @ 64 x 64) ----------------
__global__ void k_gemm2(const float* __restrict__ a, const float* __restrict__ W,
                        float* __restrict__ out) {
    __shared__ float Ws[HID * HID];
    for (int j = threadIdx.x; j < HID * HID; j += blockDim.x) Ws[j] = W[j];
    __syncthreads();
    int gid = blockIdx.x * blockDim.x + threadIdx.x;
    if (gid >= NN * HID) return;
    int n = gid >> 6, hc = gid & 63;
    const float* ar = &a[n * HID];
    float acc = 0.f;
#pragma unroll 8
    for (int k = 0; k < HID; k++) acc += ar[k] * Ws[k * HID + hc];
    out[gid] = acc;
}

// ---- layer-2 aggregation: ONE WAVE PER NODE.  lane = grp*16 + c4; the 4 groups
//      stride the edge list (4 edges concurrently in flight via lanes, zero VGPR
//      cost), then cross-group shfl reduce.  grp0 does self-loop + bias + bn2 +
//      relu + pool atomics. ----
__global__ void k_gather_w(const float* __restrict__ h, const float* __restrict__ dinv,
                           const int* __restrict__ row_ptr, const int2* __restrict__ csr,
                           const float* __restrict__ bias,
                           const float* __restrict__ gamma, const float* __restrict__ beta,
                           const float* __restrict__ mean, const float* __restrict__ var,
                           const int* __restrict__ batch,
                           float* pool, float* cnt) {
    int tid = blockIdx.x * blockDim.x + threadIdx.x;
    int n = tid >> 6;                    // one wave (64 lanes) per node
    if (n >= NN) return;
    int lane = threadIdx.x & 63;
    int grp = lane >> 4, c4 = lane & 15;
    const float4* h4 = (const float4*)h;
    int beg = row_ptr[n], end = row_ptr[n + 1];
    float4 acc = make_float4(0.f, 0.f, 0.f, 0.f);
    for (int i = beg + grp; i < end; i += 4) {
        int2 ef = csr[i];
        float w = __int_as_float(ef.y);
        float4 hv = h4[ef.x * 16 + c4];
        acc.x += w * hv.x; acc.y += w * hv.y;
        acc.z += w * hv.z; acc.w += w * hv.w;
    }
    // reduce across the 4 groups (same c4, different grp)
    acc.x += __shfl_xor(acc.x, 16); acc.y += __shfl_xor(acc.y, 16);
    acc.z += __shfl_xor(acc.z, 16); acc.w += __shfl_xor(acc.w, 16);
    acc.x += __shfl_xor(acc.x, 32); acc.y += __shfl_xor(acc.y, 32);
    acc.z += __shfl_xor(acc.z, 32); acc.w += __shfl_xor(acc.w, 32);

    if (grp == 0) {
        float di = dinv[n];
        float coef = di * di;
        float4 sv = h4[n * 16 + c4];
        float4 bv = ((const float4*)bias)[c4];
        int c0 = c4 * 4;
        float v0 = bv.x + coef * sv.x + acc.x;
        float v1 = bv.y + coef * sv.y + acc.y;
        float v2 = bv.z + coef * sv.z + acc.z;
        float v3 = bv.w + coef * sv.w + acc.w;
        float r0 = fmaxf((v0 - mean[c0 + 0]) * rsqrtf(var[c0 + 0] + EPSV) * gamma[c0 + 0] + beta[c0 + 0], 0.f);
        float r1 = fmaxf((v1 - mean[c0 + 1]) * rsqrtf(var[c0 + 1] + EPSV) * gamma[c0 + 1] + beta[c0 + 1], 0.f);
        float r2 = fmaxf((v2 - mean[c0 + 2]) * rsqrtf(var[c0 + 2] + EPSV) * gamma[c0 + 2] + beta[c0 + 2], 0.f);
        float r3 = fmaxf((v3 - mean[c0 + 3]) * rsqrtf(var[c0 + 3] + EPSV) * gamma[c0 + 3] + beta[c0 + 3], 0.f);
        int g = batch[n];
        float* pp = &pool[g * HID + c0];
        atomicAdd(pp + 0, r0);
        atomicAdd(pp + 1, r1);
        atomicAdd(pp + 2, r2);
        atomicAdd(pp + 3, r3);
        if (c4 == 0) atomicAdd(&cnt[g], 1.0f);
    }
}

// ---------------- final MLP ----------------
__global__ void k_mlp(const float* __restrict__ pool_sums, const float* __restrict__ cnt,
                      const float* __restrict__ l1W, const float* __restrict__ l1b,
                      const float* __restrict__ l2W, const float* __restrict__ l2b,
                      float* __restrict__ outp) {
    int g = blockIdx.x * blockDim.x + threadIdx.x;
    if (g >= NG) return;
    float c = fmaxf(cnt[g], 1.0f);
    float inv = 1.0f / c;
    float p[HID];
#pragma unroll
    for (int k = 0; k < HID; k++) p[k] = pool_sums[g * HID + k] * inv;
    float acc = 0.f;
    for (int j = 0; j < HID / 2; j++) {
        float z = l1b[j];
#pragma unroll 8
        for (int k = 0; k < HID; k++) z += p[k] * l1W[k * (HID / 2) + j];
        acc += fmaxf(z, 0.f) * l2W[j];
    }
    outp[g] = acc + l2b[0];
}

extern "C" void kernel_launch(void* const* d_in, const int* in_sizes, int n_in,
                              void* d_out, int out_size, void* d_ws, size_t ws_size,
                              hipStream_t stream) {
    const float* x   = (const float*)d_in[0];
    const int*   ei  = (const int*)d_in[1];
    const float* ew  = (const float*)d_in[2];
    const int*   bat = (const int*)d_in[3];
    const float* W1  = (const float*)d_in[4];
    const float* b1  = (const float*)d_in[5];
    const float* W2  = (const float*)d_in[6];
    const float* b2  = (const float*)d_in[7];
    const float* g1  = (const float*)d_in[8];
    const float* be1 = (const float*)d_in[9];
    const float* m1  = (const float*)d_in[10];
    const float* v1  = (const float*)d_in[11];
    const float* g2  = (const float*)d_in[12];
    const float* be2 = (const float*)d_in[13];
    const float* m2  = (const float*)d_in[14];
    const float* v2  = (const float*)d_in[15];
    const float* l1W = (const float*)d_in[16];
    const float* l1b = (const float*)d_in[17];
    const float* l2W = (const float*)d_in[18];
    const float* l2b = (const float*)d_in[19];
    float* out = (float*)d_out;

    const int* src = ei;
    const int* dst = ei + NE;

    // ---- workspace layout (4-byte units) ----
    float* f = (float*)d_ws;
    float* dinv    = f + 0;               // 50000 (zeroed -> rsqrt(deg+1))
    float* pool    = f + 50000;           // 8192
    float* cnt     = f + 58192;           // 128
    int*   row_ptr = (int*)(f + 58320);   // 50001
    int*   cursor  = (int*)(f + 108321);  // 50000
    // zero region = [0, 158321) floats
    int2*  csr     = (int2*)(f + 158336); // 800000 int2
    float* bufA    = f + 1758336;         // NN*HID (h2 projected) — px/xa alias here
    float* px      = f + 1758336;         // NN*8 (dead before gemm2 writes bufA)
    float* xa      = f + 2158336;         // NN*8 (dead before gemm2 writes bufA)
    float* bufC    = f + 4958336;         // NN*HID (layer-1 activated)
    // total = 8158336 floats = 32.6 MB

    const int BLK = 256;
    const int gN   = (NN + BLK - 1) / BLK;
    const int gE   = (NE + BLK - 1) / BLK;
    const int gNH  = (NN * HID + BLK - 1) / BLK;
    const int gN16 = (NN * 16 + BLK - 1) / BLK;
    const int gN64 = (NN * 64 + BLK - 1) / BLK;

    hipMemsetAsync(d_ws, 0, 158321 * sizeof(float), stream);

    // normalization + CSR build (shared across both conv layers)
    k_deg_hist<<<gE, BLK, 0, stream>>>(dst, ew, dinv, row_ptr);
    k_dinv<<<gN, BLK, 0, stream>>>(dinv);
    k_scan<<<1, SCAN_T, 0, stream>>>(row_ptr);
    k_fill<<<gE, BLK, 0, stream>>>(src, dst, ew, dinv, row_ptr, cursor, csr);

    // layer 1: aggregate raw x (5-wide) then project (+bias+bn1+relu fused)
    k_pad_x<<<gN, BLK, 0, stream>>>(x, px);
    k_gather_x<<<gN16, BLK, 0, stream>>>(px, dinv, row_ptr, csr, xa);
    k_gemm1_fused<<<gNH, BLK, 0, stream>>>(xa, W1, b1, g1, be1, m1, v1, bufC);

    // layer 2: project, then wave-per-node gather (+bias+bn2+relu+pool fused)
    k_gemm2<<<gNH, BLK, 0, stream>>>(bufC, W2, bufA);
    k_gather_w<<<gN64, BLK, 0, stream>>>(bufA, dinv, row_ptr, csr, b2,
                                         g2, be2, m2, v2, bat, pool, cnt);

    // MLP head
    k_mlp<<<1, 128, 0, stream>>>(pool, cnt, l1W, l1b, l2W, l2b, out);
}

// Round 5
// 529.733 us; speedup vs baseline: 1.1370x; 1.1105x over previous
//
#include <hip/hip_runtime.h>
#include <hip/hip_fp16.h>

#define NN 50000
#define NE 800000
#define NG 128
#define IND 5
#define HID 64
#define EPSV 1e-5f
#define SCAN_T 1024

// ---- fused degree accumulate + dst histogram ----
__global__ void k_deg_hist(const int* __restrict__ dst, const float* __restrict__ w,
                           float* deg, int* hist) {
    int e = blockIdx.x * blockDim.x + threadIdx.x;
    if (e < NE) {
        int d = dst[e];
        atomicAdd(&deg[d], w[e]);
        atomicAdd(&hist[d + 1], 1);
    }
}

// deg was zero-init; self-loop adds 1 -> dinv = rsqrt(deg+1)
__global__ void k_dinv(float* deg) {
    int i = blockIdx.x * blockDim.x + threadIdx.x;
    if (i < NN) deg[i] = rsqrtf(deg[i] + 1.0f);
}

// ---- single-block inclusive scan of row_ptr[0..NN] ----
__global__ void k_scan(int* __restrict__ row_ptr) {
    __shared__ int tot[SCAN_T];
    int t = threadIdx.x;
    const int CH = (NN + 1 + SCAN_T - 1) / SCAN_T;
    int beg = t * CH;
    int end = beg + CH; if (end > NN + 1) end = NN + 1;
    int s = 0;
    for (int i = beg; i < end; i++) s += row_ptr[i];
    tot[t] = s;
    __syncthreads();
    for (int off = 1; off < SCAN_T; off <<= 1) {
        int v = (t >= off) ? tot[t - off] : 0;
        __syncthreads();
        tot[t] += v;
        __syncthreads();
    }
    int run = (t > 0) ? tot[t - 1] : 0;
    for (int i = beg; i < end; i++) { run += row_ptr[i]; row_ptr[i] = run; }
}

// ---- bin edges into CSR (src + fused norm), keyed by dst ----
__global__ void k_fill(const int* __restrict__ src, const int* __restrict__ dst,
                       const float* __restrict__ ew, const float* __restrict__ dinv,
                       const int* __restrict__ row_ptr, int* cursor, int2* __restrict__ csr) {
    int e = blockIdx.x * blockDim.x + threadIdx.x;
    if (e >= NE) return;
    int s = src[e], d = dst[e];
    int pos = row_ptr[d] + atomicAdd(&cursor[d], 1);
    float norm = dinv[s] * ew[e] * dinv[d];
    csr[pos] = make_int2(s, __float_as_int(norm));
}

// ---- pad x (N x 5) into px (N x 8, zero-padded) for aligned float4 gathers ----
__global__ void k_pad_x(const float* __restrict__ x, float* __restrict__ px) {
    int n = blockIdx.x * blockDim.x + threadIdx.x;
    if (n >= NN) return;
    float4 a, b;
    a.x = x[n * IND + 0]; a.y = x[n * IND + 1]; a.z = x[n * IND + 2]; a.w = x[n * IND + 3];
    b.x = x[n * IND + 4]; b.y = 0.f; b.z = 0.f; b.w = 0.f;
    ((float4*)px)[n * 2 + 0] = a;
    ((float4*)px)[n * 2 + 1] = b;
}

// ---- layer-1 aggregation on RAW x (aggregate-then-project), 16 lanes/node,
//      one edge per lane (stride 16), csr prefetched one step ahead. ----
__global__ void k_gather_x(const float* __restrict__ px, const float* __restrict__ dinv,
                           const int* __restrict__ row_ptr, const int2* __restrict__ csr,
                           float* __restrict__ xa) {
    int gid = blockIdx.x * blockDim.x + threadIdx.x;  // NN*16 threads
    if (gid >= NN * 16) return;
    int n = gid >> 4, lane16 = gid & 15;
    const float4* p4 = (const float4*)px;
    int beg = row_ptr[n], end = row_ptr[n + 1];
    float4 a0 = make_float4(0.f, 0.f, 0.f, 0.f);
    float a4 = 0.f;
    int i = beg + lane16;
    if (i < end) {
        int2 cur = csr[i];
        for (; i < end; i += 16) {
            int pi = (i + 16 < end) ? i + 16 : i;
            int2 nxt = csr[pi];                 // independent, overlaps h wait
            float w = __int_as_float(cur.y);
            float4 v0 = p4[cur.x * 2 + 0];
            float  v4 = px[cur.x * 8 + 4];
            a0.x += w * v0.x; a0.y += w * v0.y; a0.z += w * v0.z; a0.w += w * v0.w;
            a4 += w * v4;
            cur = nxt;
        }
    }
#pragma unroll
    for (int m = 8; m >= 1; m >>= 1) {
        a0.x += __shfl_xor(a0.x, m); a0.y += __shfl_xor(a0.y, m);
        a0.z += __shfl_xor(a0.z, m); a0.w += __shfl_xor(a0.w, m);
        a4 += __shfl_xor(a4, m);
    }
    if (lane16 == 0) {
        float di = dinv[n];
        float coef = di * di;
        float4 v0 = p4[n * 2 + 0];
        float  v4 = px[n * 8 + 4];
        float4 o0;
        o0.x = a0.x + coef * v0.x; o0.y = a0.y + coef * v0.y;
        o0.z = a0.z + coef * v0.z; o0.w = a0.w + coef * v0.w;
        ((float4*)xa)[n * 2 + 0] = o0;
        ((float4*)xa)[n * 2 + 1] = make_float4(a4 + coef * v4, 0.f, 0.f, 0.f);
    }
}

// ---- fused projection + bias + bn1 + relu:  out = relu(bn1(xa @ W1 + b1)) ----
__global__ void k_gemm1_fused(const float* __restrict__ xa, const float* __restrict__ W1,
                              const float* __restrict__ b1,
                              const float* __restrict__ gamma, const float* __restrict__ beta,
                              const float* __restrict__ mean, const float* __restrict__ var,
                              float* __restrict__ outv) {
    __shared__ float Ws[IND * HID];
    for (int j = threadIdx.x; j < IND * HID; j += blockDim.x) Ws[j] = W1[j];
    __syncthreads();
    int gid = blockIdx.x * blockDim.x + threadIdx.x;
    if (gid >= NN * HID) return;
    int n = gid >> 6, hc = gid & 63;
    const float* xr = &xa[n * 8];
    float acc = b1[hc];
#pragma unroll
    for (int k = 0; k < IND; k++) acc += xr[k] * Ws[k * HID + hc];
    float r = fmaxf((acc - mean[hc]) * rsqrtf(var[hc] + EPSV) * gamma[hc] + beta[hc], 0.f);
    outv[gid] = r;
}

// ---- a @ W2, output compressed to fp16 (gather table: 6.4 MB instead of 12.8) ----
__global__ void k_gemm2_h16(const float* __restrict__ a, const float* __restrict__ W,
                            __half* __restrict__ out) {
    __shared__ float Ws[HID * HID];
    for (int j = threadIdx.x; j < HID * HID; j += blockDim.x) Ws[j] = W[j];
    __syncthreads();
    int gid = blockIdx.x * blockDim.x + threadIdx.x;
    if (gid >= NN * HID) return;
    int n = gid >> 6, hc = gid & 63;
    const float* ar = &a[n * HID];
    float acc = 0.f;
#pragma unroll 8
    for (int k = 0; k < HID; k++) acc += ar[k] * Ws[k * HID + hc];
    out[gid] = __float2half(acc);
}

// ---- layer-2 aggregation: 16 lanes/node serial edge loop (R2-proven shape),
//      fp16 features (8 B/lane/edge), csr prefetched one step ahead.
//      Epilogue: self-loop + bias + bn2 + relu + pool atomics. ----
__global__ void k_gather_w(const __half* __restrict__ h16, const float* __restrict__ dinv,
                           const int* __restrict__ row_ptr, const int2* __restrict__ csr,
                           const float* __restrict__ bias,
                           const float* __restrict__ gamma, const float* __restrict__ beta,
                           const float* __restrict__ mean, const float* __restrict__ var,
                           const int* __restrict__ batch,
                           float* pool, float* cnt) {
    int gid = blockIdx.x * blockDim.x + threadIdx.x;  // NN*16 threads
    if (gid >= NN * 16) return;
    int n = gid >> 4, c4 = gid & 15;
    const uint2* h8 = (const uint2*)h16;   // 16 uint2 (8 B) per 64-wide row
    int beg = row_ptr[n], end = row_ptr[n + 1];

    // self-loop term issues early, overlaps edge loop
    float di = dinv[n];
    float coef = di * di;
    uint2 sraw = h8[n * 16 + c4];
    float4 bv = ((const float4*)bias)[c4];
    float2 s01 = __half22float2(*(const __half2*)&sraw.x);
    float2 s23 = __half22float2(*(const __half2*)&sraw.y);
    float4 acc;
    acc.x = bv.x + coef * s01.x;
    acc.y = bv.y + coef * s01.y;
    acc.z = bv.z + coef * s23.x;
    acc.w = bv.w + coef * s23.y;

    if (beg < end) {
        int2 cur = csr[beg];
        for (int i = beg; i < end; i++) {
            int pi = (i + 1 < end) ? i + 1 : i;
            int2 nxt = csr[pi];                 // independent of cur, overlaps h wait
            float w = __int_as_float(cur.y);
            uint2 raw = h8[cur.x * 16 + c4];
            float2 f01 = __half22float2(*(const __half2*)&raw.x);
            float2 f23 = __half22float2(*(const __half2*)&raw.y);
            acc.x += w * f01.x; acc.y += w * f01.y;
            acc.z += w * f23.x; acc.w += w * f23.y;
            cur = nxt;
        }
    }

    int c0 = c4 * 4;
    float r0 = fmaxf((acc.x - mean[c0 + 0]) * rsqrtf(var[c0 + 0] + EPSV) * gamma[c0 + 0] + beta[c0 + 0], 0.f);
    float r1 = fmaxf((acc.y - mean[c0 + 1]) * rsqrtf(var[c0 + 1] + EPSV) * gamma[c0 + 1] + beta[c0 + 1], 0.f);
    float r2 = fmaxf((acc.z - mean[c0 + 2]) * rsqrtf(var[c0 + 2] + EPSV) * gamma[c0 + 2] + beta[c0 + 2], 0.f);
    float r3 = fmaxf((acc.w - mean[c0 + 3]) * rsqrtf(var[c0 + 3] + EPSV) * gamma[c0 + 3] + beta[c0 + 3], 0.f);
    int g = batch[n];
    float* pp = &pool[g * HID + c0];
    atomicAdd(pp + 0, r0);
    atomicAdd(pp + 1, r1);
    atomicAdd(pp + 2, r2);
    atomicAdd(pp + 3, r3);
    if (c4 == 0) atomicAdd(&cnt[g], 1.0f);
}

// ---------------- final MLP ----------------
__global__ void k_mlp(const float* __restrict__ pool_sums, const float* __restrict__ cnt,
                      const float* __restrict__ l1W, const float* __restrict__ l1b,
                      const float* __restrict__ l2W, const float* __restrict__ l2b,
                      float* __restrict__ outp) {
    int g = blockIdx.x * blockDim.x + threadIdx.x;
    if (g >= NG) return;
    float c = fmaxf(cnt[g], 1.0f);
    float inv = 1.0f / c;
    float p[HID];
#pragma unroll
    for (int k = 0; k < HID; k++) p[k] = pool_sums[g * HID + k] * inv;
    float acc = 0.f;
    for (int j = 0; j < HID / 2; j++) {
        float z = l1b[j];
#pragma unroll 8
        for (int k = 0; k < HID; k++) z += p[k] * l1W[k * (HID / 2) + j];
        acc += fmaxf(z, 0.f) * l2W[j];
    }
    outp[g] = acc + l2b[0];
}

extern "C" void kernel_launch(void* const* d_in, const int* in_sizes, int n_in,
                              void* d_out, int out_size, void* d_ws, size_t ws_size,
                              hipStream_t stream) {
    const float* x   = (const float*)d_in[0];
    const int*   ei  = (const int*)d_in[1];
    const float* ew  = (const float*)d_in[2];
    const int*   bat = (const int*)d_in[3];
    const float* W1  = (const float*)d_in[4];
    const float* b1  = (const float*)d_in[5];
    const float* W2  = (const float*)d_in[6];
    const float* b2  = (const float*)d_in[7];
    const float* g1  = (const float*)d_in[8];
    const float* be1 = (const float*)d_in[9];
    const float* m1  = (const float*)d_in[10];
    const float* v1  = (const float*)d_in[11];
    const float* g2  = (const float*)d_in[12];
    const float* be2 = (const float*)d_in[13];
    const float* m2  = (const float*)d_in[14];
    const float* v2  = (const float*)d_in[15];
    const float* l1W = (const float*)d_in[16];
    const float* l1b = (const float*)d_in[17];
    const float* l2W = (const float*)d_in[18];
    const float* l2b = (const float*)d_in[19];
    float* out = (float*)d_out;

    const int* src = ei;
    const int* dst = ei + NE;

    // ---- workspace layout (4-byte units) ----
    float* f = (float*)d_ws;
    float* dinv    = f + 0;               // 50000 (zeroed -> rsqrt(deg+1))
    float* pool    = f + 50000;           // 8192
    float* cnt     = f + 58192;           // 128
    int*   row_ptr = (int*)(f + 58320);   // 50001
    int*   cursor  = (int*)(f + 108321);  // 50000
    // zero region = [0, 158321) floats
    int2*  csr     = (int2*)(f + 158336); // 800000 int2 -> ends 1758336
    float* px      = f + 1758336;         // NN*8
    float* xa      = f + 2158336;         // NN*8
    float* bufC    = f + 2558336;         // NN*HID fp32 (layer-1 activated)
    __half* h16    = (__half*)(f + 5758336); // NN*HID fp16 (layer-2 gather table)
    // total = 7358336 floats = 29.4 MB

    const int BLK = 256;
    const int gN   = (NN + BLK - 1) / BLK;
    const int gE   = (NE + BLK - 1) / BLK;
    const int gNH  = (NN * HID + BLK - 1) / BLK;
    const int gN16 = (NN * 16 + BLK - 1) / BLK;

    hipMemsetAsync(d_ws, 0, 158321 * sizeof(float), stream);

    // normalization + CSR build (shared across both conv layers)
    k_deg_hist<<<gE, BLK, 0, stream>>>(dst, ew, dinv, row_ptr);
    k_dinv<<<gN, BLK, 0, stream>>>(dinv);
    k_scan<<<1, SCAN_T, 0, stream>>>(row_ptr);
    k_fill<<<gE, BLK, 0, stream>>>(src, dst, ew, dinv, row_ptr, cursor, csr);

    // layer 1: aggregate raw x (5-wide) then project (+bias+bn1+relu fused)
    k_pad_x<<<gN, BLK, 0, stream>>>(x, px);
    k_gather_x<<<gN16, BLK, 0, stream>>>(px, dinv, row_ptr, csr, xa);
    k_gemm1_fused<<<gNH, BLK, 0, stream>>>(xa, W1, b1, g1, be1, m1, v1, bufC);

    // layer 2: project to fp16, gather (+bias+bn2+relu+pool fused)
    k_gemm2_h16<<<gNH, BLK, 0, stream>>>(bufC, W2, h16);
    k_gather_w<<<gN16, BLK, 0, stream>>>(h16, dinv, row_ptr, csr, b2,
                                         g2, be2, m2, v2, bat, pool, cnt);

    // MLP head
    k_mlp<<<1, 128, 0, stream>>>(pool, cnt, l1W, l1b, l2W, l2b, out);
}